// Round 13
// baseline (250.005 us; speedup 1.0000x reference)
//
#include <hip/hip_runtime.h>
#include <hip/hip_bf16.h>
#include <math.h>

#define D      512
#define BQ     128
#define KK     3
#define THR    0.15f
#define SSCALE 5.0f
#define SENT   0x7fffffff
#define NBLK   256
#define TR     32              // img rows per tile (N=200000 = 6250*32 exact)
#define NB4    (NBLK * 4)
#define IDXM   0x3FFFFu

using bf16x8 = __attribute__((ext_vector_type(8))) short;
using f32x4  = __attribute__((ext_vector_type(4))) float;

__device__ __forceinline__ unsigned short f2bf(float x) {
    unsigned u = __float_as_uint(x);
    return (unsigned short)((u + 0x7fffu + ((u >> 16) & 1u)) >> 16);
}

__device__ __forceinline__ unsigned pk2(float lo, float hi) {
    __hip_bfloat162 h = __float22bfloat162_rn(make_float2(lo, hi));
    union { __hip_bfloat162 h; unsigned u; } c; c.h = h;
    return c.u;
}

__device__ __forceinline__ bf16x8 cvt8(float4 f0, float4 f1) {
    union { unsigned u[4]; bf16x8 v; } r;
    r.u[0] = pk2(f0.x, f0.y);
    r.u[1] = pk2(f0.z, f0.w);
    r.u[2] = pk2(f1.x, f1.y);
    r.u[3] = pk2(f1.z, f1.w);
    return r.v;
}

// ordered-float: monotone u32 mapping of f32
__device__ __forceinline__ unsigned ordf(float v) {
    unsigned u = __float_as_uint(v);
    return u ^ ((unsigned)((int)u >> 31) | 0x80000000u);
}

// guarded descending insert into a 4-key list (keys pack value|~idx: tie -> lower idx wins)
__device__ __forceinline__ void insk4(unsigned key, unsigned K[4]) {
    if (key > K[3]) {
        bool b0 = key > K[0], b1 = key > K[1], b2 = key > K[2];
        unsigned k0 = K[0], k1 = K[1], k2 = K[2];
        K[0] = b0 ? key : k0;
        K[1] = b0 ? k0 : (b1 ? key : k1);
        K[2] = b1 ? k1 : (b2 ? key : k2);
        K[3] = b2 ? k2 : key;
    }
}

__device__ __forceinline__ void insk8(unsigned key, unsigned* K) {
    if (key <= K[7]) return;
    #pragma unroll
    for (int k = 0; k < 8; ++k) {
        if (key > K[k]) {
            #pragma unroll
            for (int m = 7; m > k; --m) K[m] = K[m-1];
            K[k] = key;
            return;
        }
    }
}

// exact float top-4 with (value desc, idx asc) tie rule — matches jax.lax.top_k
template<int K>
__device__ __forceinline__ void insK(float v, int c, float* V, int* C) {
    #pragma unroll
    for (int k = 0; k < K; ++k) {
        if (v > V[k] || (v == V[k] && c < C[k])) {
            #pragma unroll
            for (int m = K - 1; m > k; --m) { V[m] = V[m-1]; C[m] = C[m-1]; }
            V[k] = v; C[k] = c;
            return;
        }
    }
}

// ---------------- kernel 1: normalize i_feats + query bf16 fragment image ----------------
// apre slot (c, w, kg, lr) at uint4 index (c*8 + w)*64 + kg*16 + lr: bf16 of
// ihat[q = w*16+lr][k = c*32 + kg*8 .. +8].  A wave's frag read (lane = kg*16+lr)
// of frag c is CONTIGUOUS 1 KB.
__global__ void prep_kernel(const float* __restrict__ x, float* __restrict__ ihat,
                            uint4* __restrict__ apre) {
    int r = blockIdx.x;
    int l = threadIdx.x;             // 0..63, owns k = l*8 .. +8  (c = l>>2, kg = l&3)
    const float4* row = (const float4*)(x + (size_t)r * D);
    float4 v0 = row[l * 2 + 0];
    float4 v1 = row[l * 2 + 1];
    float s = v0.x*v0.x + v0.y*v0.y + v0.z*v0.z + v0.w*v0.w
            + v1.x*v1.x + v1.y*v1.y + v1.z*v1.z + v1.w*v1.w;
    #pragma unroll
    for (int off = 32; off > 0; off >>= 1) s += __shfl_xor(s, off);
    float inv = 1.0f / sqrtf(s);
    float a0 = v0.x*inv, a1 = v0.y*inv, a2 = v0.z*inv, a3 = v0.w*inv;
    float a4 = v1.x*inv, a5 = v1.y*inv, a6 = v1.z*inv, a7 = v1.w*inv;
    float4* orow = (float4*)(ihat + (size_t)r * D);
    orow[l*2+0] = make_float4(a0, a1, a2, a3);
    orow[l*2+1] = make_float4(a4, a5, a6, a7);
    uint4 p;
    p.x = f2bf(a0) | ((unsigned)f2bf(a1) << 16);
    p.y = f2bf(a2) | ((unsigned)f2bf(a3) << 16);
    p.z = f2bf(a4) | ((unsigned)f2bf(a5) << 16);
    p.w = f2bf(a6) | ((unsigned)f2bf(a7) << 16);
    apre[((l >> 2) * 8 + (r >> 4)) * 64 + (l & 3) * 16 + (r & 15)] = p;
}

// ---------------- kernel 2: DMA-staged MFMA sim + packed-key top-4 ----------------
// R13: invert the data movement. img tiles (32 rows x 2 KB = 64 KB) are staged to
// LDS by global_load_lds width-16 with FULLY CONTIGUOUS global reads (the R8-R12
// 2-KB-lane-strided pattern pinned HBM at 2.2 TB/s; more waves / order pinning both
// failed => address-pattern-bound). LDS dest is linear; the bank swizzle
// (byte ^ (row&7)<<4) is folded into the per-lane *source* address (same line set,
// coalescing intact). Queries live in 64 VGPRs per wave (tile-invariant, loaded
// once; each of 8 waves owns 16 queries) -> no query LDS, vmcnt carries only the
// DMA stream. Double-buffered tiles, one __syncthreads per tile.
__global__ __launch_bounds__(512)
void sim_topk(const uint4* __restrict__ apre, const float* __restrict__ img,
              int N, int ntiles, unsigned* __restrict__ pk)
{
    extern __shared__ __align__(16) unsigned char Bs[];   // 2 x 65536
    const int tid  = threadIdx.x;
    const int lane = tid & 63;
    const int wid  = tid >> 6;          // 0..7
    const int lr   = lane & 15;
    const int kg   = lane >> 4;
    const int bid  = blockIdx.x;

    // wave's 16 query B-frags (queries wid*16 .. +16), contiguous 1-KB loads
    bf16x8 qf[16];
    #pragma unroll
    for (int c = 0; c < 16; ++c)
        qf[c] = *(const bf16x8*)(apre + (c * 8 + wid) * 64 + lane);

    unsigned keys[4] = {0u, 0u, 0u, 0u};

    const int nit = (ntiles > bid) ? ((ntiles - bid + NBLK - 1) / NBLK) : 0;

    // per-lane constant LDS read offsets (XOR swizzle in bits 4-6)
    const int oz0 = (kg * 32 +  0) ^ ((lr & 7) << 4);
    const int oz1 = (kg * 32 + 16) ^ ((lr & 7) << 4);

#define STAGE(tt, bb) do {                                                     \
        size_t rbase_ = (size_t)(tt) * TR;                                     \
        _Pragma("unroll")                                                      \
        for (int i_ = 0; i_ < 8; ++i_) {                                       \
            int s_ = wid * 8 + i_;            /* 1-KB segment 0..63 */         \
            int row_ = s_ >> 1, half_ = s_ & 1;                                \
            size_t rg_ = rbase_ + row_;                                        \
            if (rg_ >= (size_t)N) rg_ = N - 1;                                 \
            int so_ = (half_ * 1024 + (lane << 4)) ^ ((row_ & 7) << 4);        \
            const float* g_ = img + rg_ * D + (so_ >> 2);                      \
            __builtin_amdgcn_global_load_lds(                                  \
                (const __attribute__((address_space(1))) unsigned int*)g_,     \
                (__attribute__((address_space(3))) unsigned int*)               \
                    (Bs + (bb) * 65536 + s_ * 1024),                           \
                16, 0, 0);                                                     \
        }                                                                      \
    } while (0)

#define COMPUTE(tt, bb) do {                                                   \
        const unsigned char* A0_ = Bs + (bb) * 65536 + lr * 2048;              \
        const unsigned char* A1_ = A0_ + 16 * 2048;                            \
        f32x4 ac0 = (f32x4){0.f,0.f,0.f,0.f};                                  \
        f32x4 ac1 = (f32x4){0.f,0.f,0.f,0.f};                                  \
        float s0 = 0.f, s1 = 0.f;                                              \
        _Pragma("unroll")                                                      \
        for (int c_ = 0; c_ < 16; ++c_) {                                      \
            float4 p0 = *(const float4*)(A0_ + oz0 + c_ * 128);                \
            float4 p1 = *(const float4*)(A0_ + oz1 + c_ * 128);                \
            float4 q0 = *(const float4*)(A1_ + oz0 + c_ * 128);                \
            float4 q1 = *(const float4*)(A1_ + oz1 + c_ * 128);                \
            s0 += p0.x*p0.x + p0.y*p0.y + p0.z*p0.z + p0.w*p0.w                \
                + p1.x*p1.x + p1.y*p1.y + p1.z*p1.z + p1.w*p1.w;               \
            s1 += q0.x*q0.x + q0.y*q0.y + q0.z*q0.z + q0.w*q0.w                \
                + q1.x*q1.x + q1.y*q1.y + q1.z*q1.z + q1.w*q1.w;               \
            bf16x8 af0 = cvt8(p0, p1);                                         \
            bf16x8 af1 = cvt8(q0, q1);                                         \
            ac0 = __builtin_amdgcn_mfma_f32_16x16x32_bf16(af0, qf[c_], ac0, 0, 0, 0); \
            ac1 = __builtin_amdgcn_mfma_f32_16x16x32_bf16(af1, qf[c_], ac1, 0, 0, 0); \
        }                                                                      \
        s0 += __shfl_xor(s0, 16); s0 += __shfl_xor(s0, 32);                    \
        s1 += __shfl_xor(s1, 16); s1 += __shfl_xor(s1, 32);                    \
        float rn0 = s0 > 0.f ? rsqrtf(s0) : 0.f;                               \
        float rn1 = s1 > 0.f ? rsqrtf(s1) : 0.f;                               \
        _Pragma("unroll")                                                      \
        for (int rg_ = 0; rg_ < 4; ++rg_) {                                    \
            int ri_ = kg * 4 + rg_;                                            \
            float w0_ = __shfl(rn0, ri_);                                      \
            float w1_ = __shfl(rn1, ri_);                                      \
            int i0_ = (tt) * TR + ri_;                                         \
            int i1_ = i0_ + 16;                                                \
            if (i0_ < N) {                                                     \
                unsigned k0_ = (ordf(ac0[rg_] * w0_) & 0xFFFC0000u)            \
                             | ((unsigned)i0_ ^ IDXM);                         \
                insk4(k0_, keys);                                              \
            }                                                                  \
            if (i1_ < N) {                                                     \
                unsigned k1_ = (ordf(ac1[rg_] * w1_) & 0xFFFC0000u)            \
                             | ((unsigned)i1_ ^ IDXM);                         \
                insk4(k1_, keys);                                              \
            }                                                                  \
        }                                                                      \
    } while (0)

    int buf = 0;
    if (nit > 0) STAGE(bid, 0);
    __syncthreads();
    for (int it = 0; it < nit; ++it) {
        int t = bid + it * NBLK;
        if (it + 1 < nit) STAGE(t + NBLK, buf ^ 1);
        COMPUTE(t, buf);
        __syncthreads();      // drains next tile's DMA; releases buf for restage
        buf ^= 1;
    }
#undef STAGE
#undef COMPUTE

    // merge the 4 kg lanes holding the same query, then write block top-4
    #pragma unroll
    for (int st = 0; st < 2; ++st) {
        const int off = st ? 32 : 16;
        unsigned mk[4];
        #pragma unroll
        for (int s = 0; s < 4; ++s) mk[s] = __shfl_xor((int)keys[s], off);
        #pragma unroll
        for (int s = 0; s < 4; ++s) insk4(mk[s], keys);
    }
    if (kg == 0) {
        int q = wid * 16 + lr;
        uint4 o; o.x = keys[0]; o.y = keys[1]; o.z = keys[2]; o.w = keys[3];
        *(uint4*)(pk + (size_t)q * NB4 + (size_t)bid * 4) = o;
    }
}

// ---------------- kernel 3: reduce keys -> top-8 -> exact fp32 rescore -> weights ----
__global__ __launch_bounds__(256)
void reduce_rescore(const unsigned* __restrict__ pk, int nb4,
                    const float* __restrict__ ihat, const float* __restrict__ img, int N,
                    float* __restrict__ swo, int* __restrict__ sidxo,
                    int* __restrict__ valido)
{
    __shared__ unsigned lk[256][8];
    __shared__ float sv[8];
    __shared__ int   si[8];
    const int r = blockIdx.x, tid = threadIdx.x;

    unsigned K[8];
    #pragma unroll
    for (int k = 0; k < 8; ++k) K[k] = 0u;
    const unsigned* prow = pk + (size_t)r * nb4;
    for (int j = tid; j < nb4; j += 256) insk8(prow[j], K);
    #pragma unroll
    for (int k = 0; k < 8; ++k) lk[tid][k] = K[k];
    __syncthreads();
    if (tid < 16) {
        for (int o = 1; o < 16; ++o) {
            int t2 = tid + o * 16;
            #pragma unroll
            for (int s = 0; s < 8; ++s) insk8(lk[t2][s], K);
        }
        #pragma unroll
        for (int k = 0; k < 8; ++k) lk[tid][k] = K[k];
    }
    __syncthreads();
    if (tid == 0) {
        for (int o = 1; o < 16; ++o)
            #pragma unroll
            for (int s = 0; s < 8; ++s) insk8(lk[o][s], K);
        #pragma unroll
        for (int k = 0; k < 8; ++k) {
            int idx = (int)((K[k] & IDXM) ^ IDXM);
            si[k] = (K[k] != 0u && idx < N) ? idx : -1;
        }
    }
    __syncthreads();

    // exact fp32 rescore of the 8 candidates (32 lanes each)
    {
        const int k = tid >> 5, l = tid & 31;
        int idx = si[k];
        float dot = 0.f, ssq = 0.f;
        if (idx >= 0) {
            const float* a = ihat + (size_t)r * D + l * 16;
            const float* b = img + (size_t)idx * D + l * 16;
            #pragma unroll
            for (int j = 0; j < 4; ++j) {
                float4 va = *(const float4*)(a + j*4);
                float4 vb = *(const float4*)(b + j*4);
                dot += va.x*vb.x + va.y*vb.y + va.z*vb.z + va.w*vb.w;
                ssq += vb.x*vb.x + vb.y*vb.y + vb.z*vb.z + vb.w*vb.w;
            }
        }
        #pragma unroll
        for (int o = 16; o > 0; o >>= 1) { dot += __shfl_xor(dot, o); ssq += __shfl_xor(ssq, o); }
        if (l == 0) sv[k] = (idx >= 0 && ssq > 0.f) ? dot * rsqrtf(ssq) : -1e30f;
    }
    __syncthreads();

    if (tid == 0) {
        float Vt[4]; int Ct[4];
        #pragma unroll
        for (int k = 0; k < 4; ++k) { Vt[k] = -1e30f; Ct[k] = SENT; }
        #pragma unroll
        for (int k = 0; k < 8; ++k)
            if (si[k] >= 0) insK<4>(sv[k], si[k], Vt, Ct);
        float lg[4]; int vd[3];
        lg[0] = SSCALE;
        #pragma unroll
        for (int k = 0; k < 3; ++k) {
            vd[k] = (Vt[k+1] > THR) ? 1 : 0;
            lg[k+1] = vd[k] ? SSCALE * Vt[k+1] : -1e30f;
        }
        float m = fmaxf(fmaxf(lg[0], lg[1]), fmaxf(lg[2], lg[3]));
        float e0 = expf(lg[0]-m), e1 = expf(lg[1]-m), e2 = expf(lg[2]-m), e3 = expf(lg[3]-m);
        float sum = e0 + e1 + e2 + e3;
        float ee[3] = {e1, e2, e3};
        #pragma unroll
        for (int k = 0; k < 3; ++k) {
            float w = 1.0f - ee[k] / sum;
            swo[r*3+k]    = vd[k] ? w : 0.0f;
            sidxo[r*3+k]  = vd[k] ? Ct[k+1] : 0;
            valido[r*3+k] = vd[k];
        }
    }
}

// ---------------- kernel 4: assemble output (1536 x 512 fp32) ----------------
__global__ void assemble_kernel(const float* __restrict__ i_feats, const float* __restrict__ t_feats,
                                const float* __restrict__ img, const float* __restrict__ txt,
                                const float* __restrict__ sw, const int* __restrict__ sidx,
                                const int* __restrict__ valid, float* __restrict__ out)
{
    const int r = blockIdx.x;      // 0..1535
    const int t = threadIdx.x;     // 0..127
    float4* orow = (float4*)(out + (size_t)r * D);
    if (r < 128) {
        orow[t] = ((const float4*)(i_feats + (size_t)r * D))[t];
    } else if (r < 512) {
        int s = r - 128;
        float4 v = make_float4(0.f,0.f,0.f,0.f);
        if (valid[s]) v = ((const float4*)(img + (size_t)sidx[s] * D))[t];
        orow[t] = v;
    } else if (r < 640) {
        orow[t] = ((const float4*)(t_feats + (size_t)(r - 512) * D))[t];
    } else if (r < 1024) {
        int s = r - 640;
        float4 v = make_float4(0.f,0.f,0.f,0.f);
        if (valid[s]) v = ((const float4*)(txt + (size_t)sidx[s] * D))[t];
        orow[t] = v;
    } else {
        int li = r - 1024;
        float o[4];
        int j0 = t * 4;
        if (li < 128) {
            #pragma unroll
            for (int u = 0; u < 4; ++u) {
                int j = j0 + u;
                if (j < 128) o[u] = (j == li) ? 1.0f : 0.0f;
                else {
                    int s = j - 128;
                    o[u] = (s / 3 == li) ? sw[li*3 + (s % 3)] : 0.0f;
                }
            }
        } else {
            int i2 = li - 128;
            int b = i2 / 3;
            int vi = valid[i2];
            #pragma unroll
            for (int u = 0; u < 4; ++u) {
                int j = j0 + u;
                float val;
                if (j < 128) val = (vi && j == b) ? 1.0f : 0.0f;
                else {
                    int s2 = j - 128;
                    int vj = valid[s2];
                    int b2 = s2 / 3;
                    if (vi && vj)        val = (b == b2) ? 1.0f : 0.0f;
                    else if (!vi && !vj) val = (i2 == s2) ? 1.0f : 0.0f;
                    else                 val = 0.0f;
                }
                o[u] = val;
            }
        }
        orow[t] = make_float4(o[0], o[1], o[2], o[3]);
    }
}

extern "C" void kernel_launch(void* const* d_in, const int* in_sizes, int n_in,
                              void* d_out, int out_size, void* d_ws, size_t ws_size,
                              hipStream_t stream) {
    const float* i_feats = (const float*)d_in[0];
    const float* t_feats = (const float*)d_in[1];
    const float* img     = (const float*)d_in[2];
    const float* txt     = (const float*)d_in[3];
    float* out = (float*)d_out;

    const int N      = in_sizes[2] / D;        // 200000
    const int ntiles = (N + TR - 1) / TR;      // 6250

    char* ws = (char*)d_ws;
    size_t off = 0;
    float*    ihat = (float*)(ws + off);    off += (size_t)BQ * D * 4;    // 256 KB
    uint4*    apre = (uint4*)(ws + off);    off += (size_t)BQ * D * 2;    // 128 KB
    unsigned* pk   = (unsigned*)(ws + off); off += (size_t)BQ * NB4 * 4;  // 512 KB
    float*    swv  = (float*)(ws + off);    off += BQ * 4 * 4;
    int*      sidx = (int*)(ws + off);      off += BQ * 4 * 4;
    int*      vld  = (int*)(ws + off);      off += BQ * 4 * 4;

    prep_kernel<<<BQ, 64, 0, stream>>>(i_feats, ihat, apre);
    sim_topk<<<NBLK, 512, 131072, stream>>>(apre, img, N, ntiles, pk);
    reduce_rescore<<<BQ, 256, 0, stream>>>(pk, NB4, ihat, img, N, swv, sidx, vld);
    assemble_kernel<<<3 * (BQ + BQ * KK), 128, 0, stream>>>(i_feats, t_feats, img, txt,
                                                            swv, sidx, vld, out);
}

// Round 14
// 243.257 us; speedup vs baseline: 1.0277x; 1.0277x over previous
//
#include <hip/hip_runtime.h>
#include <hip/hip_bf16.h>
#include <math.h>

#define D      512
#define BQ     128
#define KK     3
#define THR    0.15f
#define SSCALE 5.0f
#define SENT   0x7fffffff
#define NBLK   256               // tile-groups; grid = 2*NBLK (query halves)
#define NSTR   (NBLK * 8)        // 2048 tile streams per query-half
#define NB4    (NBLK * 4)
#define IDXM   0x3FFFFu

using bf16x8 = __attribute__((ext_vector_type(8))) short;
using f32x4  = __attribute__((ext_vector_type(4))) float;

__device__ __forceinline__ unsigned short f2bf(float x) {
    unsigned u = __float_as_uint(x);
    return (unsigned short)((u + 0x7fffu + ((u >> 16) & 1u)) >> 16);
}

__device__ __forceinline__ unsigned pk2(float lo, float hi) {
    __hip_bfloat162 h = __float22bfloat162_rn(make_float2(lo, hi));
    union { __hip_bfloat162 h; unsigned u; } c; c.h = h;
    return c.u;
}

__device__ __forceinline__ bf16x8 cvt8(float4 f0, float4 f1) {
    union { unsigned u[4]; bf16x8 v; } r;
    r.u[0] = pk2(f0.x, f0.y);
    r.u[1] = pk2(f0.z, f0.w);
    r.u[2] = pk2(f1.x, f1.y);
    r.u[3] = pk2(f1.z, f1.w);
    return r.v;
}

// ordered-float: monotone u32 mapping of f32
__device__ __forceinline__ unsigned ordf(float v) {
    unsigned u = __float_as_uint(v);
    return u ^ ((unsigned)((int)u >> 31) | 0x80000000u);
}

// guarded descending insert into a 4-key list (keys pack value|~idx: tie -> lower idx wins)
__device__ __forceinline__ void insk4(unsigned key, unsigned K[4]) {
    if (key > K[3]) {
        bool b0 = key > K[0], b1 = key > K[1], b2 = key > K[2];
        unsigned k0 = K[0], k1 = K[1], k2 = K[2];
        K[0] = b0 ? key : k0;
        K[1] = b0 ? k0 : (b1 ? key : k1);
        K[2] = b1 ? k1 : (b2 ? key : k2);
        K[3] = b2 ? k2 : key;
    }
}

__device__ __forceinline__ void insk8(unsigned key, unsigned* K) {
    if (key <= K[7]) return;
    #pragma unroll
    for (int k = 0; k < 8; ++k) {
        if (key > K[k]) {
            #pragma unroll
            for (int m = 7; m > k; --m) K[m] = K[m-1];
            K[k] = key;
            return;
        }
    }
}

// exact float top-4 with (value desc, idx asc) tie rule — matches jax.lax.top_k
template<int K>
__device__ __forceinline__ void insK(float v, int c, float* V, int* C) {
    #pragma unroll
    for (int k = 0; k < K; ++k) {
        if (v > V[k] || (v == V[k] && c < C[k])) {
            #pragma unroll
            for (int m = K - 1; m > k; --m) { V[m] = V[m-1]; C[m] = C[m-1]; }
            V[k] = v; C[k] = c;
            return;
        }
    }
}

// ---------------- kernel 1: normalize i_feats + query bf16 fragment image ----------------
// apre element (q, c, g) at index g*2048 + c*128 + q  (16B each): bf16 of
// ihat[q][k], k = c*32 + g*8 .. +8
__global__ void prep_kernel(const float* __restrict__ x, float* __restrict__ ihat,
                            uint4* __restrict__ apre) {
    int r = blockIdx.x;
    int l = threadIdx.x;             // 0..63, owns k = l*8 .. +8  (c = l>>2, g = l&3)
    const float4* row = (const float4*)(x + (size_t)r * D);
    float4 v0 = row[l * 2 + 0];
    float4 v1 = row[l * 2 + 1];
    float s = v0.x*v0.x + v0.y*v0.y + v0.z*v0.z + v0.w*v0.w
            + v1.x*v1.x + v1.y*v1.y + v1.z*v1.z + v1.w*v1.w;
    #pragma unroll
    for (int off = 32; off > 0; off >>= 1) s += __shfl_xor(s, off);
    float inv = 1.0f / sqrtf(s);
    float a0 = v0.x*inv, a1 = v0.y*inv, a2 = v0.z*inv, a3 = v0.w*inv;
    float a4 = v1.x*inv, a5 = v1.y*inv, a6 = v1.z*inv, a7 = v1.w*inv;
    float4* orow = (float4*)(ihat + (size_t)r * D);
    orow[l*2+0] = make_float4(a0, a1, a2, a3);
    orow[l*2+1] = make_float4(a4, a5, a6, a7);
    uint4 p;
    p.x = f2bf(a0) | ((unsigned)f2bf(a1) << 16);
    p.y = f2bf(a2) | ((unsigned)f2bf(a3) << 16);
    p.z = f2bf(a4) | ((unsigned)f2bf(a5) << 16);
    p.w = f2bf(a6) | ((unsigned)f2bf(a7) << 16);
    apre[((l & 3) << 11) + ((l >> 2) << 7) + r] = p;
}

// ---------------- kernel 2: split-query streaming MFMA sim + packed-key top-4 ----------
// R14: the 128-KB query matrix forced 1 block/CU in R5-R13, capping the CU at ~8
// independent request streams -> HBM plateau ~2.5-2.8 TB/s regardless of address
// pattern (R13), wave count in one block (R12), or issue order (R11). Split queries:
// each block owns 64 queries (64 KB LDS) -> 2 blocks/CU, 512 blocks, 16 independent
// streams/CU. Blocks tg and tg+256 stream the SAME tiles and sit on the same XCD
// (256%8==0, co-resident) -> duplicate img reads merge in L1/L2; FETCH_SIZE detects
// merge failure (410 vs 820 MB). No hot-loop barriers, no wave pairing. Per-wave
// state ~95 VGPR < 128 cap. LDS layout [c:16][g:4][q':64]x16B (R8-verified
// conflict-free pattern).
__global__ __launch_bounds__(512)
void sim_topk(const uint4* __restrict__ apre, const float* __restrict__ img,
              int N, int ntiles, int nit, unsigned* __restrict__ pk)
{
    __shared__ __align__(16) unsigned char Bs[65536];
    const int tid  = threadIdx.x;
    const int lane = tid & 63;
    const int wid  = tid >> 6;          // 0..7: independent tile stream
    const int lr   = lane & 15;
    const int kg   = lane >> 4;
    const int qh   = blockIdx.x >> 8;   // query half: 0 or 1
    const int tg   = blockIdx.x & 255;  // tile group

    // stage this half's query frags -> LDS: (q',c,g) at c*4096 + g*1024 + q'*16
    #pragma unroll
    for (int j = 0; j < 8; ++j) {
        int s = tid + j * 512;          // 0..4095
        int q_ = s & 63, c = (s >> 6) & 15, g = s >> 10;
        uint4 p = apre[g * 2048 + c * 128 + qh * 64 + q_];
        *(uint4*)(Bs + c * 4096 + g * 1024 + q_ * 16) = p;
    }
    __syncthreads();

    // frag(nf, c) = Bs + c*4096 + lane_off + nf*256 ; local query q' = nf*16 + lr
    const int lane_off = kg * 1024 + lr * 16;

    // per-lane running top-4 keys for 4 local queries
    unsigned keys[4][4];
    #pragma unroll
    for (int nf = 0; nf < 4; ++nf)
        #pragma unroll
        for (int s = 0; s < 4; ++s) keys[nf][s] = 0u;

    int t = tg * 8 + wid;
    const float* gp;
    {
        int row = t * 16 + lr;
        if (row >= N) row = N - 1;
        gp = img + (size_t)row * D + kg * 8;
    }

    float4 pre[4][2];
    if (t < ntiles) {
        #pragma unroll
        for (int c = 0; c < 4; ++c) {
            pre[c][0] = *(const float4*)(gp + c * 32);
            pre[c][1] = *(const float4*)(gp + c * 32 + 4);
        }
    }

#define CHUNK(c) do {                                                          \
        float4 f0_ = pre[(c) & 3][0], f1_ = pre[(c) & 3][1];                   \
        if ((c) < 12) {                                                        \
            pre[(c) & 3][0] = *(const float4*)(gp + ((c) + 4) * 32);           \
            pre[(c) & 3][1] = *(const float4*)(gp + ((c) + 4) * 32 + 4);       \
        } else {                                                               \
            pre[(c) & 3][0] = *(const float4*)(gpn + ((c) - 12) * 32);         \
            pre[(c) & 3][1] = *(const float4*)(gpn + ((c) - 12) * 32 + 4);     \
        }                                                                      \
        sq += f0_.x*f0_.x + f0_.y*f0_.y + f0_.z*f0_.z + f0_.w*f0_.w            \
            + f1_.x*f1_.x + f1_.y*f1_.y + f1_.z*f1_.z + f1_.w*f1_.w;           \
        bf16x8 a_ = cvt8(f0_, f1_);                                            \
        const unsigned char* bp_ = Bs + (c) * 4096 + lane_off;                 \
        _Pragma("unroll")                                                      \
        for (int nf_ = 0; nf_ < 4; ++nf_) {                                    \
            bf16x8 b_ = *(const bf16x8*)(bp_ + nf_ * 256);                     \
            acc[nf_] = __builtin_amdgcn_mfma_f32_16x16x32_bf16(a_, b_, acc[nf_], 0, 0, 0); \
        }                                                                      \
    } while (0)

    for (int it = 0; it < nit; ++it) {
        int tn = t + NSTR;
        if (t < ntiles) {
            const float* gpn;
            {
                int tt = (tn < ntiles) ? tn : t;
                int row = tt * 16 + lr;
                if (row >= N) row = N - 1;
                gpn = img + (size_t)row * D + kg * 8;
            }
            f32x4 acc[4];
            #pragma unroll
            for (int nf = 0; nf < 4; ++nf) acc[nf] = (f32x4){0.f, 0.f, 0.f, 0.f};
            float sq = 0.f;

            CHUNK(0);  CHUNK(1);  CHUNK(2);  CHUNK(3);
            CHUNK(4);  CHUNK(5);  CHUNK(6);  CHUNK(7);
            CHUNK(8);  CHUNK(9);  CHUNK(10); CHUNK(11);
            CHUNK(12); CHUNK(13); CHUNK(14); CHUNK(15);

            // row norms: lane's sq covers its row's kg-slices; butterfly over kg lanes
            float s2 = sq;
            s2 += __shfl_xor(s2, 16);
            s2 += __shfl_xor(s2, 32);
            float rnorm = s2 > 0.f ? rsqrtf(s2) : 0.f;

            const int ib = t * 16 + kg * 4;
            #pragma unroll
            for (int g = 0; g < 4; ++g) {
                int idx = ib + g;
                bool ok = idx < N;
                unsigned ic = (unsigned)idx ^ IDXM;
                float r = __shfl(rnorm, kg * 4 + g);
                #pragma unroll
                for (int nf = 0; nf < 4; ++nf) {
                    unsigned o   = ordf(acc[nf][g] * r);
                    unsigned key = ok ? ((o & 0xFFFC0000u) | ic) : 0u;
                    insk4(key, keys[nf]);
                }
            }
            gp = gpn;
        }
        t = tn;
    }
#undef CHUNK

    // merge across the 4 kg lane-groups (same query lives in lanes lr, lr+16, lr+32, lr+48)
    #pragma unroll
    for (int nf = 0; nf < 4; ++nf) {
        #pragma unroll
        for (int st = 0; st < 2; ++st) {
            const int off = st ? 32 : 16;
            unsigned mk[4];
            #pragma unroll
            for (int s = 0; s < 4; ++s) mk[s] = __shfl_xor((int)keys[nf][s], off);
            #pragma unroll
            for (int s = 0; s < 4; ++s) insk4(mk[s], keys[nf]);
        }
    }

    // block-level merge in LDS (query buffer dead now): slot (wid, q'), 8 waves x 64 q
    __syncthreads();
    if (kg == 0) {
        #pragma unroll
        for (int nf = 0; nf < 4; ++nf) {
            int q_ = nf * 16 + lr;
            uint4 v;
            v.x = keys[nf][0]; v.y = keys[nf][1]; v.z = keys[nf][2]; v.w = keys[nf][3];
            *(uint4*)(Bs + ((size_t)wid * 64 + q_) * 16) = v;
        }
    }
    __syncthreads();
    if (tid < 64) {
        int q_ = tid;
        unsigned V[4] = {0u, 0u, 0u, 0u};
        #pragma unroll
        for (int w = 0; w < 8; ++w) {
            uint4 kk = *(const uint4*)(Bs + ((size_t)w * 64 + q_) * 16);
            insk4(kk.x, V); insk4(kk.y, V); insk4(kk.z, V); insk4(kk.w, V);
        }
        int q = qh * 64 + q_;
        uint4 o; o.x = V[0]; o.y = V[1]; o.z = V[2]; o.w = V[3];
        *(uint4*)(pk + (size_t)q * NB4 + (size_t)tg * 4) = o;
    }
}

// ---------------- kernel 3: reduce keys -> top-8 -> exact fp32 rescore -> weights ----
__global__ __launch_bounds__(256)
void reduce_rescore(const unsigned* __restrict__ pk, int nb4,
                    const float* __restrict__ ihat, const float* __restrict__ img, int N,
                    float* __restrict__ swo, int* __restrict__ sidxo,
                    int* __restrict__ valido)
{
    __shared__ unsigned lk[256][8];
    __shared__ float sv[8];
    __shared__ int   si[8];
    const int r = blockIdx.x, tid = threadIdx.x;

    unsigned K[8];
    #pragma unroll
    for (int k = 0; k < 8; ++k) K[k] = 0u;
    const unsigned* prow = pk + (size_t)r * nb4;
    for (int j = tid; j < nb4; j += 256) insk8(prow[j], K);
    #pragma unroll
    for (int k = 0; k < 8; ++k) lk[tid][k] = K[k];
    __syncthreads();
    if (tid < 16) {
        for (int o = 1; o < 16; ++o) {
            int t2 = tid + o * 16;
            #pragma unroll
            for (int s = 0; s < 8; ++s) insk8(lk[t2][s], K);
        }
        #pragma unroll
        for (int k = 0; k < 8; ++k) lk[tid][k] = K[k];
    }
    __syncthreads();
    if (tid == 0) {
        for (int o = 1; o < 16; ++o)
            #pragma unroll
            for (int s = 0; s < 8; ++s) insk8(lk[o][s], K);
        #pragma unroll
        for (int k = 0; k < 8; ++k) {
            int idx = (int)((K[k] & IDXM) ^ IDXM);
            si[k] = (K[k] != 0u && idx < N) ? idx : -1;
        }
    }
    __syncthreads();

    // exact fp32 rescore of the 8 candidates (32 lanes each)
    {
        const int k = tid >> 5, l = tid & 31;
        int idx = si[k];
        float dot = 0.f, ssq = 0.f;
        if (idx >= 0) {
            const float* a = ihat + (size_t)r * D + l * 16;
            const float* b = img + (size_t)idx * D + l * 16;
            #pragma unroll
            for (int j = 0; j < 4; ++j) {
                float4 va = *(const float4*)(a + j*4);
                float4 vb = *(const float4*)(b + j*4);
                dot += va.x*vb.x + va.y*vb.y + va.z*vb.z + va.w*vb.w;
                ssq += vb.x*vb.x + vb.y*vb.y + vb.z*vb.z + vb.w*vb.w;
            }
        }
        #pragma unroll
        for (int o = 16; o > 0; o >>= 1) { dot += __shfl_xor(dot, o); ssq += __shfl_xor(ssq, o); }
        if (l == 0) sv[k] = (idx >= 0 && ssq > 0.f) ? dot * rsqrtf(ssq) : -1e30f;
    }
    __syncthreads();

    if (tid == 0) {
        float Vt[4]; int Ct[4];
        #pragma unroll
        for (int k = 0; k < 4; ++k) { Vt[k] = -1e30f; Ct[k] = SENT; }
        #pragma unroll
        for (int k = 0; k < 8; ++k)
            if (si[k] >= 0) insK<4>(sv[k], si[k], Vt, Ct);
        float lg[4]; int vd[3];
        lg[0] = SSCALE;
        #pragma unroll
        for (int k = 0; k < 3; ++k) {
            vd[k] = (Vt[k+1] > THR) ? 1 : 0;
            lg[k+1] = vd[k] ? SSCALE * Vt[k+1] : -1e30f;
        }
        float m = fmaxf(fmaxf(lg[0], lg[1]), fmaxf(lg[2], lg[3]));
        float e0 = expf(lg[0]-m), e1 = expf(lg[1]-m), e2 = expf(lg[2]-m), e3 = expf(lg[3]-m);
        float sum = e0 + e1 + e2 + e3;
        float ee[3] = {e1, e2, e3};
        #pragma unroll
        for (int k = 0; k < 3; ++k) {
            float w = 1.0f - ee[k] / sum;
            swo[r*3+k]    = vd[k] ? w : 0.0f;
            sidxo[r*3+k]  = vd[k] ? Ct[k+1] : 0;
            valido[r*3+k] = vd[k];
        }
    }
}

// ---------------- kernel 4: assemble output (1536 x 512 fp32) ----------------
__global__ void assemble_kernel(const float* __restrict__ i_feats, const float* __restrict__ t_feats,
                                const float* __restrict__ img, const float* __restrict__ txt,
                                const float* __restrict__ sw, const int* __restrict__ sidx,
                                const int* __restrict__ valid, float* __restrict__ out)
{
    const int r = blockIdx.x;      // 0..1535
    const int t = threadIdx.x;     // 0..127
    float4* orow = (float4*)(out + (size_t)r * D);
    if (r < 128) {
        orow[t] = ((const float4*)(i_feats + (size_t)r * D))[t];
    } else if (r < 512) {
        int s = r - 128;
        float4 v = make_float4(0.f,0.f,0.f,0.f);
        if (valid[s]) v = ((const float4*)(img + (size_t)sidx[s] * D))[t];
        orow[t] = v;
    } else if (r < 640) {
        orow[t] = ((const float4*)(t_feats + (size_t)(r - 512) * D))[t];
    } else if (r < 1024) {
        int s = r - 640;
        float4 v = make_float4(0.f,0.f,0.f,0.f);
        if (valid[s]) v = ((const float4*)(txt + (size_t)sidx[s] * D))[t];
        orow[t] = v;
    } else {
        int li = r - 1024;
        float o[4];
        int j0 = t * 4;
        if (li < 128) {
            #pragma unroll
            for (int u = 0; u < 4; ++u) {
                int j = j0 + u;
                if (j < 128) o[u] = (j == li) ? 1.0f : 0.0f;
                else {
                    int s = j - 128;
                    o[u] = (s / 3 == li) ? sw[li*3 + (s % 3)] : 0.0f;
                }
            }
        } else {
            int i2 = li - 128;
            int b = i2 / 3;
            int vi = valid[i2];
            #pragma unroll
            for (int u = 0; u < 4; ++u) {
                int j = j0 + u;
                float val;
                if (j < 128) val = (vi && j == b) ? 1.0f : 0.0f;
                else {
                    int s2 = j - 128;
                    int vj = valid[s2];
                    int b2 = s2 / 3;
                    if (vi && vj)        val = (b == b2) ? 1.0f : 0.0f;
                    else if (!vi && !vj) val = (i2 == s2) ? 1.0f : 0.0f;
                    else                 val = 0.0f;
                }
                o[u] = val;
            }
        }
        orow[t] = make_float4(o[0], o[1], o[2], o[3]);
    }
}

extern "C" void kernel_launch(void* const* d_in, const int* in_sizes, int n_in,
                              void* d_out, int out_size, void* d_ws, size_t ws_size,
                              hipStream_t stream) {
    const float* i_feats = (const float*)d_in[0];
    const float* t_feats = (const float*)d_in[1];
    const float* img     = (const float*)d_in[2];
    const float* txt     = (const float*)d_in[3];
    float* out = (float*)d_out;

    const int N      = in_sizes[2] / D;        // 200000
    const int ntiles = (N + 15) / 16;          // 12500
    const int nit    = (ntiles + NSTR - 1) / NSTR;   // 7

    char* ws = (char*)d_ws;
    size_t off = 0;
    float*    ihat = (float*)(ws + off);    off += (size_t)BQ * D * 4;    // 256 KB
    uint4*    apre = (uint4*)(ws + off);    off += (size_t)BQ * D * 2;    // 128 KB
    unsigned* pk   = (unsigned*)(ws + off); off += (size_t)BQ * NB4 * 4;  // 512 KB
    float*    swv  = (float*)(ws + off);    off += BQ * 4 * 4;
    int*      sidx = (int*)(ws + off);      off += BQ * 4 * 4;
    int*      vld  = (int*)(ws + off);      off += BQ * 4 * 4;

    prep_kernel<<<BQ, 64, 0, stream>>>(i_feats, ihat, apre);
    sim_topk<<<2 * NBLK, 512, 0, stream>>>(apre, img, N, ntiles, nit, pk);
    reduce_rescore<<<BQ, 256, 0, stream>>>(pk, NB4, ihat, img, N, swv, sidx, vld);
    assemble_kernel<<<3 * (BQ + BQ * KK), 128, 0, stream>>>(i_feats, t_feats, img, txt,
                                                            swv, sidx, vld, out);
}

// Round 15
// 207.591 us; speedup vs baseline: 1.2043x; 1.1718x over previous
//
#include <hip/hip_runtime.h>
#include <hip/hip_bf16.h>
#include <math.h>

#define D      512
#define BQ     128
#define KK     3
#define THR    0.15f
#define SSCALE 5.0f
#define SENT   0x7fffffff
#define NBLK   256
#define NSTR   (NBLK * 8)        // 2048 independent tile streams
#define NB4    (NBLK * 4)
#define IDXM   0x3FFFFu

using bf16x8 = __attribute__((ext_vector_type(8))) short;
using f32x4  = __attribute__((ext_vector_type(4))) float;

__device__ __forceinline__ unsigned short f2bf(float x) {
    unsigned u = __float_as_uint(x);
    return (unsigned short)((u + 0x7fffu + ((u >> 16) & 1u)) >> 16);
}

__device__ __forceinline__ unsigned pk2(float lo, float hi) {
    __hip_bfloat162 h = __float22bfloat162_rn(make_float2(lo, hi));
    union { __hip_bfloat162 h; unsigned u; } c; c.h = h;
    return c.u;
}

__device__ __forceinline__ bf16x8 cvt8(float4 f0, float4 f1) {
    union { unsigned u[4]; bf16x8 v; } r;
    r.u[0] = pk2(f0.x, f0.y);
    r.u[1] = pk2(f0.z, f0.w);
    r.u[2] = pk2(f1.x, f1.y);
    r.u[3] = pk2(f1.z, f1.w);
    return r.v;
}

// ordered-float: monotone u32 mapping of f32
__device__ __forceinline__ unsigned ordf(float v) {
    unsigned u = __float_as_uint(v);
    return u ^ ((unsigned)((int)u >> 31) | 0x80000000u);
}

// guarded descending insert into a 4-key list (keys pack value|~idx: tie -> lower idx wins)
__device__ __forceinline__ void insk4(unsigned key, unsigned K[4]) {
    if (key > K[3]) {
        bool b0 = key > K[0], b1 = key > K[1], b2 = key > K[2];
        unsigned k0 = K[0], k1 = K[1], k2 = K[2];
        K[0] = b0 ? key : k0;
        K[1] = b0 ? k0 : (b1 ? key : k1);
        K[2] = b1 ? k1 : (b2 ? key : k2);
        K[3] = b2 ? k2 : key;
    }
}

__device__ __forceinline__ void insk8(unsigned key, unsigned* K) {
    if (key <= K[7]) return;
    #pragma unroll
    for (int k = 0; k < 8; ++k) {
        if (key > K[k]) {
            #pragma unroll
            for (int m = 7; m > k; --m) K[m] = K[m-1];
            K[k] = key;
            return;
        }
    }
}

// exact float top-4 with (value desc, idx asc) tie rule — matches jax.lax.top_k
template<int K>
__device__ __forceinline__ void insK(float v, int c, float* V, int* C) {
    #pragma unroll
    for (int k = 0; k < K; ++k) {
        if (v > V[k] || (v == V[k] && c < C[k])) {
            #pragma unroll
            for (int m = K - 1; m > k; --m) { V[m] = V[m-1]; C[m] = C[m-1]; }
            V[k] = v; C[k] = c;
            return;
        }
    }
}

// ---------------- kernel 1: normalize i_feats + query bf16 fragment image ----------------
// apre element (q, c, g) at index g*2048 + c*128 + q  (16B each): bf16 of
// ihat[q][k], k = c*32 + g*8 .. +8
__global__ void prep_kernel(const float* __restrict__ x, float* __restrict__ ihat,
                            uint4* __restrict__ apre) {
    int r = blockIdx.x;
    int l = threadIdx.x;             // 0..63, owns k = l*8 .. +8  (c = l>>2, g = l&3)
    const float4* row = (const float4*)(x + (size_t)r * D);
    float4 v0 = row[l * 2 + 0];
    float4 v1 = row[l * 2 + 1];
    float s = v0.x*v0.x + v0.y*v0.y + v0.z*v0.z + v0.w*v0.w
            + v1.x*v1.x + v1.y*v1.y + v1.z*v1.z + v1.w*v1.w;
    #pragma unroll
    for (int off = 32; off > 0; off >>= 1) s += __shfl_xor(s, off);
    float inv = 1.0f / sqrtf(s);
    float a0 = v0.x*inv, a1 = v0.y*inv, a2 = v0.z*inv, a3 = v0.w*inv;
    float a4 = v1.x*inv, a5 = v1.y*inv, a6 = v1.z*inv, a7 = v1.w*inv;
    float4* orow = (float4*)(ihat + (size_t)r * D);
    orow[l*2+0] = make_float4(a0, a1, a2, a3);
    orow[l*2+1] = make_float4(a4, a5, a6, a7);
    uint4 p;
    p.x = f2bf(a0) | ((unsigned)f2bf(a1) << 16);
    p.y = f2bf(a2) | ((unsigned)f2bf(a3) << 16);
    p.z = f2bf(a4) | ((unsigned)f2bf(a5) << 16);
    p.w = f2bf(a6) | ((unsigned)f2bf(a7) << 16);
    apre[((l & 3) << 11) + ((l >> 2) << 7) + r] = p;
}

// ---------------- kernel 2: unique-stream MFMA sim + packed-key top-4 ----------------
// R15 discriminating probe: R8's structure (8 INDEPENDENT waves, each streaming its
// own tiles against all 128 queries -> img read exactly once, no duplication, no
// hot-loop barriers) with prefetch depth 2 (pre[2][2], crossover 14) so register
// demand ~112 < 128 -> no spill (R8's depth-4 spilled 412 MB which polluted the
// measurement). Unique in-flight/CU = 32 KB (= R9's unique), 8 streams/CU (2x R9).
// Models: (D) duplication wasted BW -> sim ~90us; (P) unique-rate platform cap
// ~2.5 TB/s -> sim ~165us, declare plateau next round.
__global__ __launch_bounds__(512)
void sim_topk(const uint4* __restrict__ apre, const float* __restrict__ img,
              int N, int ntiles, int nit, unsigned* __restrict__ pk)
{
    extern __shared__ __align__(16) unsigned char Bs[];   // 131072 B
    const int tid  = threadIdx.x;
    const int lane = tid & 63;
    const int wid  = tid >> 6;
    const int lr   = lane & 15;
    const int kg   = lane >> 4;

    // stage query frags -> LDS (one-time): element (q,c,g) at c*8192 + g*2048 + q*16
    #pragma unroll
    for (int j = 0; j < 16; ++j) {
        int s = tid + j * 512;                 // 0..8191
        uint4 p = apre[s];
        int addr = ((s >> 7) & 15) * 8192 + (s >> 11) * 2048 + (s & 127) * 16;
        *(uint4*)(Bs + addr) = p;
    }
    __syncthreads();

    // frag(nf, c) = Bs + c*8192 + lane_off + nf*256  (16 consecutive lanes x 256B: conflict-free)
    const int lane_off = kg * 2048 + lr * 16;

    // per-lane running top-4 keys for 8 queries (q = nf*16 + lr)
    unsigned keys[8][4];
    #pragma unroll
    for (int nf = 0; nf < 8; ++nf)
        #pragma unroll
        for (int s = 0; s < 4; ++s) keys[nf][s] = 0u;

    int t = blockIdx.x * 8 + wid;
    const float* gp;
    {
        int row = t * 16 + lr;
        if (row >= N) row = N - 1;
        gp = img + (size_t)row * D + kg * 8;
    }

    float4 pre[2][2];
    if (t < ntiles) {
        #pragma unroll
        for (int c = 0; c < 2; ++c) {
            pre[c][0] = *(const float4*)(gp + c * 32);
            pre[c][1] = *(const float4*)(gp + c * 32 + 4);
        }
    }

#define CHUNK(c) do {                                                          \
        float4 f0_ = pre[(c) & 1][0], f1_ = pre[(c) & 1][1];                   \
        if ((c) < 14) {                                                        \
            pre[(c) & 1][0] = *(const float4*)(gp + ((c) + 2) * 32);           \
            pre[(c) & 1][1] = *(const float4*)(gp + ((c) + 2) * 32 + 4);       \
        } else {                                                               \
            pre[(c) & 1][0] = *(const float4*)(gpn + ((c) - 14) * 32);         \
            pre[(c) & 1][1] = *(const float4*)(gpn + ((c) - 14) * 32 + 4);     \
        }                                                                      \
        sq += f0_.x*f0_.x + f0_.y*f0_.y + f0_.z*f0_.z + f0_.w*f0_.w            \
            + f1_.x*f1_.x + f1_.y*f1_.y + f1_.z*f1_.z + f1_.w*f1_.w;           \
        bf16x8 a_ = cvt8(f0_, f1_);                                            \
        const unsigned char* bp_ = Bs + (c) * 8192 + lane_off;                 \
        _Pragma("unroll")                                                      \
        for (int nf_ = 0; nf_ < 8; ++nf_) {                                    \
            bf16x8 b_ = *(const bf16x8*)(bp_ + nf_ * 256);                     \
            acc[nf_] = __builtin_amdgcn_mfma_f32_16x16x32_bf16(a_, b_, acc[nf_], 0, 0, 0); \
        }                                                                      \
    } while (0)

    for (int it = 0; it < nit; ++it) {
        int tn = t + NSTR;
        if (t < ntiles) {
            const float* gpn;
            {
                int tt = (tn < ntiles) ? tn : t;
                int row = tt * 16 + lr;
                if (row >= N) row = N - 1;
                gpn = img + (size_t)row * D + kg * 8;
            }
            f32x4 acc[8];
            #pragma unroll
            for (int nf = 0; nf < 8; ++nf) acc[nf] = (f32x4){0.f, 0.f, 0.f, 0.f};
            float sq = 0.f;

            CHUNK(0);  CHUNK(1);  CHUNK(2);  CHUNK(3);
            CHUNK(4);  CHUNK(5);  CHUNK(6);  CHUNK(7);
            CHUNK(8);  CHUNK(9);  CHUNK(10); CHUNK(11);
            CHUNK(12); CHUNK(13); CHUNK(14); CHUNK(15);

            // row norms: lane's sq covers its row's kg-slices; butterfly over kg lanes
            float s2 = sq;
            s2 += __shfl_xor(s2, 16);
            s2 += __shfl_xor(s2, 32);
            float rnorm = s2 > 0.f ? rsqrtf(s2) : 0.f;

            const int ib = t * 16 + kg * 4;
            #pragma unroll
            for (int g = 0; g < 4; ++g) {
                int idx = ib + g;
                bool ok = idx < N;
                unsigned ic = (unsigned)idx ^ IDXM;
                float r = __shfl(rnorm, kg * 4 + g);
                #pragma unroll
                for (int nf = 0; nf < 8; ++nf) {
                    unsigned o   = ordf(acc[nf][g] * r);
                    unsigned key = ok ? ((o & 0xFFFC0000u) | ic) : 0u;
                    insk4(key, keys[nf]);
                }
            }
            gp = gpn;
        }
        t = tn;
    }
#undef CHUNK

    // merge across the 4 kg lane-groups (same query lives in lanes lr, lr+16, lr+32, lr+48)
    #pragma unroll
    for (int nf = 0; nf < 8; ++nf) {
        #pragma unroll
        for (int st = 0; st < 2; ++st) {
            const int off = st ? 32 : 16;
            unsigned mk[4];
            #pragma unroll
            for (int s = 0; s < 4; ++s) mk[s] = __shfl_xor((int)keys[nf][s], off);
            #pragma unroll
            for (int s = 0; s < 4; ++s) insk4(mk[s], keys[nf]);
        }
    }

    // block-level merge in LDS (query buffer dead now)
    __syncthreads();
    if (kg == 0) {
        #pragma unroll
        for (int nf = 0; nf < 8; ++nf) {
            int q = nf * 16 + lr;
            uint4 v;
            v.x = keys[nf][0]; v.y = keys[nf][1]; v.z = keys[nf][2]; v.w = keys[nf][3];
            *(uint4*)(Bs + ((size_t)wid * 128 + q) * 16) = v;
        }
    }
    __syncthreads();
    if (tid < BQ) {
        int q = tid;
        unsigned V[4] = {0u, 0u, 0u, 0u};
        #pragma unroll
        for (int w = 0; w < 8; ++w) {
            uint4 kk = *(const uint4*)(Bs + ((size_t)w * 128 + q) * 16);
            insk4(kk.x, V); insk4(kk.y, V); insk4(kk.z, V); insk4(kk.w, V);
        }
        uint4 o; o.x = V[0]; o.y = V[1]; o.z = V[2]; o.w = V[3];
        *(uint4*)(pk + (size_t)q * NB4 + (size_t)blockIdx.x * 4) = o;
    }
}

// ---------------- kernel 3: reduce keys -> top-8 -> exact fp32 rescore -> weights ----
__global__ __launch_bounds__(256)
void reduce_rescore(const unsigned* __restrict__ pk, int nb4,
                    const float* __restrict__ ihat, const float* __restrict__ img, int N,
                    float* __restrict__ swo, int* __restrict__ sidxo,
                    int* __restrict__ valido)
{
    __shared__ unsigned lk[256][8];
    __shared__ float sv[8];
    __shared__ int   si[8];
    const int r = blockIdx.x, tid = threadIdx.x;

    unsigned K[8];
    #pragma unroll
    for (int k = 0; k < 8; ++k) K[k] = 0u;
    const unsigned* prow = pk + (size_t)r * nb4;
    for (int j = tid; j < nb4; j += 256) insk8(prow[j], K);
    #pragma unroll
    for (int k = 0; k < 8; ++k) lk[tid][k] = K[k];
    __syncthreads();
    if (tid < 16) {
        for (int o = 1; o < 16; ++o) {
            int t2 = tid + o * 16;
            #pragma unroll
            for (int s = 0; s < 8; ++s) insk8(lk[t2][s], K);
        }
        #pragma unroll
        for (int k = 0; k < 8; ++k) lk[tid][k] = K[k];
    }
    __syncthreads();
    if (tid == 0) {
        for (int o = 1; o < 16; ++o)
            #pragma unroll
            for (int s = 0; s < 8; ++s) insk8(lk[o][s], K);
        #pragma unroll
        for (int k = 0; k < 8; ++k) {
            int idx = (int)((K[k] & IDXM) ^ IDXM);
            si[k] = (K[k] != 0u && idx < N) ? idx : -1;
        }
    }
    __syncthreads();

    // exact fp32 rescore of the 8 candidates (32 lanes each)
    {
        const int k = tid >> 5, l = tid & 31;
        int idx = si[k];
        float dot = 0.f, ssq = 0.f;
        if (idx >= 0) {
            const float* a = ihat + (size_t)r * D + l * 16;
            const float* b = img + (size_t)idx * D + l * 16;
            #pragma unroll
            for (int j = 0; j < 4; ++j) {
                float4 va = *(const float4*)(a + j*4);
                float4 vb = *(const float4*)(b + j*4);
                dot += va.x*vb.x + va.y*vb.y + va.z*vb.z + va.w*vb.w;
                ssq += vb.x*vb.x + vb.y*vb.y + vb.z*vb.z + vb.w*vb.w;
            }
        }
        #pragma unroll
        for (int o = 16; o > 0; o >>= 1) { dot += __shfl_xor(dot, o); ssq += __shfl_xor(ssq, o); }
        if (l == 0) sv[k] = (idx >= 0 && ssq > 0.f) ? dot * rsqrtf(ssq) : -1e30f;
    }
    __syncthreads();

    if (tid == 0) {
        float Vt[4]; int Ct[4];
        #pragma unroll
        for (int k = 0; k < 4; ++k) { Vt[k] = -1e30f; Ct[k] = SENT; }
        #pragma unroll
        for (int k = 0; k < 8; ++k)
            if (si[k] >= 0) insK<4>(sv[k], si[k], Vt, Ct);
        float lg[4]; int vd[3];
        lg[0] = SSCALE;
        #pragma unroll
        for (int k = 0; k < 3; ++k) {
            vd[k] = (Vt[k+1] > THR) ? 1 : 0;
            lg[k+1] = vd[k] ? SSCALE * Vt[k+1] : -1e30f;
        }
        float m = fmaxf(fmaxf(lg[0], lg[1]), fmaxf(lg[2], lg[3]));
        float e0 = expf(lg[0]-m), e1 = expf(lg[1]-m), e2 = expf(lg[2]-m), e3 = expf(lg[3]-m);
        float sum = e0 + e1 + e2 + e3;
        float ee[3] = {e1, e2, e3};
        #pragma unroll
        for (int k = 0; k < 3; ++k) {
            float w = 1.0f - ee[k] / sum;
            swo[r*3+k]    = vd[k] ? w : 0.0f;
            sidxo[r*3+k]  = vd[k] ? Ct[k+1] : 0;
            valido[r*3+k] = vd[k];
        }
    }
}

// ---------------- kernel 4: assemble output (1536 x 512 fp32) ----------------
__global__ void assemble_kernel(const float* __restrict__ i_feats, const float* __restrict__ t_feats,
                                const float* __restrict__ img, const float* __restrict__ txt,
                                const float* __restrict__ sw, const int* __restrict__ sidx,
                                const int* __restrict__ valid, float* __restrict__ out)
{
    const int r = blockIdx.x;      // 0..1535
    const int t = threadIdx.x;     // 0..127
    float4* orow = (float4*)(out + (size_t)r * D);
    if (r < 128) {
        orow[t] = ((const float4*)(i_feats + (size_t)r * D))[t];
    } else if (r < 512) {
        int s = r - 128;
        float4 v = make_float4(0.f,0.f,0.f,0.f);
        if (valid[s]) v = ((const float4*)(img + (size_t)sidx[s] * D))[t];
        orow[t] = v;
    } else if (r < 640) {
        orow[t] = ((const float4*)(t_feats + (size_t)(r - 512) * D))[t];
    } else if (r < 1024) {
        int s = r - 640;
        float4 v = make_float4(0.f,0.f,0.f,0.f);
        if (valid[s]) v = ((const float4*)(txt + (size_t)sidx[s] * D))[t];
        orow[t] = v;
    } else {
        int li = r - 1024;
        float o[4];
        int j0 = t * 4;
        if (li < 128) {
            #pragma unroll
            for (int u = 0; u < 4; ++u) {
                int j = j0 + u;
                if (j < 128) o[u] = (j == li) ? 1.0f : 0.0f;
                else {
                    int s = j - 128;
                    o[u] = (s / 3 == li) ? sw[li*3 + (s % 3)] : 0.0f;
                }
            }
        } else {
            int i2 = li - 128;
            int b = i2 / 3;
            int vi = valid[i2];
            #pragma unroll
            for (int u = 0; u < 4; ++u) {
                int j = j0 + u;
                float val;
                if (j < 128) val = (vi && j == b) ? 1.0f : 0.0f;
                else {
                    int s2 = j - 128;
                    int vj = valid[s2];
                    int b2 = s2 / 3;
                    if (vi && vj)        val = (b == b2) ? 1.0f : 0.0f;
                    else if (!vi && !vj) val = (i2 == s2) ? 1.0f : 0.0f;
                    else                 val = 0.0f;
                }
                o[u] = val;
            }
        }
        orow[t] = make_float4(o[0], o[1], o[2], o[3]);
    }
}

extern "C" void kernel_launch(void* const* d_in, const int* in_sizes, int n_in,
                              void* d_out, int out_size, void* d_ws, size_t ws_size,
                              hipStream_t stream) {
    const float* i_feats = (const float*)d_in[0];
    const float* t_feats = (const float*)d_in[1];
    const float* img     = (const float*)d_in[2];
    const float* txt     = (const float*)d_in[3];
    float* out = (float*)d_out;

    const int N      = in_sizes[2] / D;        // 200000
    const int ntiles = (N + 15) / 16;          // 12500
    const int nit    = (ntiles + NSTR - 1) / NSTR;   // 7

    char* ws = (char*)d_ws;
    size_t off = 0;
    float*    ihat = (float*)(ws + off);    off += (size_t)BQ * D * 4;    // 256 KB
    uint4*    apre = (uint4*)(ws + off);    off += (size_t)BQ * D * 2;    // 128 KB
    unsigned* pk   = (unsigned*)(ws + off); off += (size_t)BQ * NB4 * 4;  // 512 KB
    float*    swv  = (float*)(ws + off);    off += BQ * 4 * 4;
    int*      sidx = (int*)(ws + off);      off += BQ * 4 * 4;
    int*      vld  = (int*)(ws + off);      off += BQ * 4 * 4;

    prep_kernel<<<BQ, 64, 0, stream>>>(i_feats, ihat, apre);
    sim_topk<<<NBLK, 512, 131072, stream>>>(apre, img, N, ntiles, nit, pk);
    reduce_rescore<<<BQ, 256, 0, stream>>>(pk, NB4, ihat, img, N, swv, sidx, vld);
    assemble_kernel<<<3 * (BQ + BQ * KK), 128, 0, stream>>>(i_feats, t_feats, img, txt,
                                                            swv, sidx, vld, out);
}